// Round 3
// baseline (672.926 us; speedup 1.0000x reference)
//
#include <hip/hip_runtime.h>
#include <hip/hip_bf16.h>
#include <stdint.h>

#define L_ 8
#define M_ 128
#define K_ 32
#define D_ 16
#define B_ 2048
#define N_ 1024           // L_*M_
#define SLAB_ 32768       // B_*D_ elements per node slab

// ===========================================================================
// FUSED PER-B PATH v3: state lives in `out` (L1-coherent within the block),
// LDS used for gather staging, BBLK = 8 columns per block.
// ---------------------------------------------------------------------------
// Block owns 8 consecutive batch columns. All computed-node gathers read
// out[s-1, bb, f] — lines this block itself wrote (same CU -> same L1 ->
// workgroup-scope RAW coherence across __syncthreads()). trace and out share
// the same layout, so tag0/tag2 differ only in base pointer: one uniform
// global_load path, no flat-LDS mixing.
//
// Per layer:
//   gather phase: thread (gm=tid>>3, gb=tid&7) fetches 32 k-values for its
//     (node gm, column gb) -> G[k][m][b] in LDS (stride-1 writes, no conflict)
//   FMA phase: thread (m2=tid>>3, dq=(tid>>1)&3, bq=tid&1) computes 4 d x 4 b
//     acc; g via ds_read_b128 (b-quad), W via 32 float4 from L2-resident Wt.
// W L2 traffic = B_/8 * 2 MB = 512 MB (was 4.3 GB at BBLK=2).
// ===========================================================================

__global__ __launch_bounds__(512) void prep_kernel(const float* __restrict__ W,
                                                   const int* __restrict__ sn,
                                                   const int* __restrict__ sf,
                                                   float* __restrict__ Wt,
                                                   uint32_t* __restrict__ meta) {
    int n = blockIdx.x;
    int t = threadIdx.x;          // 512 = D_*K_ ; t = d*32 + k
    int d = t >> 5;
    int k = t & 31;
    // W[n][d][k] -> Wt[n][k][d]
    Wt[(size_t)n * 512 + k * 16 + d] = W[(size_t)n * 512 + t];
    if (t < K_) {
        int s = sn[(size_t)n * K_ + t];
        int f = sf[(size_t)n * K_ + t];
        int l = n >> 7;
        uint32_t mk;
        if (s == 0) {
            mk = (1u << 30) | (uint32_t)f;                        // x
        } else if (s > (l << 7)) {
            mk = (uint32_t)((s - 1) * SLAB_ + f);                 // trace (tag 0)
        } else {
            mk = (2u << 30) | (uint32_t)((s - 1) * SLAB_ + f);    // state via out
        }
        meta[(size_t)n * K_ + t] = mk;
    }
}

__global__ __launch_bounds__(1024) void fused3_kernel(
    const float* __restrict__ x, const float* __restrict__ trace,
    const uint32_t* __restrict__ meta, const float* __restrict__ Wt,
    const float* __restrict__ bias, float* __restrict__ out)
{
    extern __shared__ float G[];      // [K_=32][M_=128][8] floats = 131072 B

    int tid = threadIdx.x;
    int bb0 = blockIdx.x << 3;        // first of this block's 8 columns

    // gather-phase coords
    int gm  = tid >> 3;               // node-in-layer 0..127
    int gb  = tid & 7;                // column slot 0..7
    int bbg = bb0 + gb;

    // FMA-phase coords
    int m2  = tid >> 3;               // node-in-layer
    int dq  = (tid >> 1) & 3;         // d quarter (4 features)
    int bq  = tid & 1;                // b quad (4 columns)

    for (int l = 0; l < L_; ++l) {
        if (l) __syncthreads();       // prev FMA done reading G; out visible

        // ---------------- gather phase -------------------------------------
        {
            const uint4* mp = (const uint4*)(meta + (((size_t)(l << 7) + gm) << 5));
            float* gdst = G + (gm << 3) + gb;
#pragma unroll
            for (int jq = 0; jq < 8; ++jq) {
                uint4 mk4 = mp[jq];
                uint32_t mk[4] = {mk4.x, mk4.y, mk4.z, mk4.w};
                float v[4];
#pragma unroll
                for (int u = 0; u < 4; ++u) {
                    uint32_t tag = mk[u] >> 30;
                    uint32_t off = (mk[u] & 0x3FFFFFFFu) + ((uint32_t)bbg << 4);
                    const float* p = (tag == 0) ? trace : ((tag == 1) ? x : out);
                    v[u] = p[off];
                }
#pragma unroll
                for (int u = 0; u < 4; ++u) {
                    gdst[((jq << 2) + u) << 10] = v[u];   // G[k][gm][gb]
                }
            }
        }
        __syncthreads();

        // ---------------- FMA phase ----------------------------------------
        {
            int n = (l << 7) + m2;
            float4 bv = *(const float4*)(bias + ((size_t)n << 4) + (dq << 2));
            // acc[d 0..3][b 0..3]
            float a00 = bv.x, a01 = bv.x, a02 = bv.x, a03 = bv.x;
            float a10 = bv.y, a11 = bv.y, a12 = bv.y, a13 = bv.y;
            float a20 = bv.z, a21 = bv.z, a22 = bv.z, a23 = bv.z;
            float a30 = bv.w, a31 = bv.w, a32 = bv.w, a33 = bv.w;

            const float4* wb = (const float4*)(Wt + ((size_t)n << 9)) + dq;
            const float*  gk = G + (m2 << 3) + (bq << 2);
#pragma unroll
            for (int k = 0; k < K_; ++k) {
                float4 g4 = *(const float4*)(gk + (k << 10));   // 4 b columns
                float4 w  = wb[k << 2];                          // 4 d features
                a00 = fmaf(g4.x, w.x, a00); a01 = fmaf(g4.y, w.x, a01);
                a02 = fmaf(g4.z, w.x, a02); a03 = fmaf(g4.w, w.x, a03);
                a10 = fmaf(g4.x, w.y, a10); a11 = fmaf(g4.y, w.y, a11);
                a12 = fmaf(g4.z, w.y, a12); a13 = fmaf(g4.w, w.y, a13);
                a20 = fmaf(g4.x, w.z, a20); a21 = fmaf(g4.y, w.z, a21);
                a22 = fmaf(g4.z, w.z, a22); a23 = fmaf(g4.w, w.z, a23);
                a30 = fmaf(g4.x, w.w, a30); a31 = fmaf(g4.y, w.w, a31);
                a32 = fmaf(g4.z, w.w, a32); a33 = fmaf(g4.w, w.w, a33);
            }

            float4 o0 = make_float4(fmaxf(a00,0.f), fmaxf(a10,0.f), fmaxf(a20,0.f), fmaxf(a30,0.f));
            float4 o1 = make_float4(fmaxf(a01,0.f), fmaxf(a11,0.f), fmaxf(a21,0.f), fmaxf(a31,0.f));
            float4 o2 = make_float4(fmaxf(a02,0.f), fmaxf(a12,0.f), fmaxf(a22,0.f), fmaxf(a32,0.f));
            float4 o3 = make_float4(fmaxf(a03,0.f), fmaxf(a13,0.f), fmaxf(a23,0.f), fmaxf(a33,0.f));

            size_t obase = (((size_t)n << 11) + bb0 + (bq << 2)) << 4;
            float* op = out + obase + (dq << 2);
            *(float4*)(op)       = o0;      // b = bq*4+0
            *(float4*)(op + 16)  = o1;      // b = bq*4+1
            *(float4*)(op + 32)  = o2;      // b = bq*4+2
            *(float4*)(op + 48)  = o3;      // b = bq*4+3
        }
    }
}

// ===========================================================================
// FALLBACK PATH (verified tiered implementation)
// ===========================================================================

__global__ __launch_bounds__(256) void transpose_bd(const float* __restrict__ trace,
                                                    const float* __restrict__ x,
                                                    float* __restrict__ traceT,
                                                    float* __restrict__ xT) {
    int blk = blockIdx.x;
    const float* src;
    float* dst;
    int bt;
    if (blk < N_ * 32) {
        int n = blk >> 5;
        src = trace + (size_t)n * SLAB_;
        dst = traceT + (size_t)n * SLAB_;
        bt  = blk & 31;
    } else {
        src = x;
        dst = xT;
        bt  = blk - N_ * 32;
    }
    int b0 = bt * 64;

    __shared__ float lds[D_][65];

    int tid = threadIdx.x;
    const float4* s4 = (const float4*)src;
    int b  = tid >> 2;
    int dq = tid & 3;
    float4 v = s4[(size_t)(b0 + b) * 4 + dq];
    lds[dq * 4 + 0][b] = v.x;
    lds[dq * 4 + 1][b] = v.y;
    lds[dq * 4 + 2][b] = v.z;
    lds[dq * 4 + 3][b] = v.w;
    __syncthreads();

    int d  = tid >> 4;
    int bq = tid & 15;
    float4 w;
    w.x = lds[d][bq * 4 + 0];
    w.y = lds[d][bq * 4 + 1];
    w.z = lds[d][bq * 4 + 2];
    w.w = lds[d][bq * 4 + 3];
    ((float4*)(dst + (size_t)d * B_ + b0))[bq] = w;
}

__global__ __launch_bounds__(256) void layer_kernel(
    int l,
    const float* __restrict__ xbuf, int xfs, int xbs,
    const float* __restrict__ tbuf, int tfs, int tbs,
    const float* __restrict__ obuf, int ofs, int obs,
    const int* __restrict__ sn, const int* __restrict__ sf,
    const float* __restrict__ W, const float* __restrict__ bias,
    float* __restrict__ out, float* __restrict__ outT, int writeT)
{
    int m  = blockIdx.x >> 3;
    int bt = blockIdx.x & 7;
    int n  = l * M_ + m;
    int b  = bt * 256 + threadIdx.x;

    __shared__ float        Wsh[D_][K_];
    __shared__ float        bsh[D_];
    __shared__ const float* colp[K_];
    __shared__ int          colbs[K_];
    __shared__ float        osh[256][17];

    int tid = threadIdx.x;

    if (tid < 128) {
        ((float4*)&Wsh[0][0])[tid] = ((const float4*)(W + (size_t)n * D_ * K_))[tid];
    }
    if (tid < D_) bsh[tid] = bias[(size_t)n * D_ + tid];
    if (tid < K_) {
        int s = sn[(size_t)n * K_ + tid];
        int f = sf[(size_t)n * K_ + tid];
        const float* p;
        int bs;
        if (s == 0) {
            p  = xbuf + (size_t)f * xfs;
            bs = xbs;
        } else {
            int ls = (s - 1) >> 7;
            if (ls >= l) {
                p  = tbuf + (size_t)(s - 1) * SLAB_ + (size_t)f * tfs;
                bs = tbs;
            } else {
                p  = obuf + (size_t)(s - 1) * SLAB_ + (size_t)f * ofs;
                bs = obs;
            }
        }
        colp[tid]  = p;
        colbs[tid] = bs;
    }
    __syncthreads();

    float g[K_];
#pragma unroll
    for (int k = 0; k < K_; ++k) {
        g[k] = colp[k][(size_t)b * colbs[k]];
    }

#pragma unroll
    for (int d = 0; d < D_; ++d) {
        float acc = bsh[d];
#pragma unroll
        for (int k = 0; k < K_; ++k) acc = fmaf(g[k], Wsh[d][k], acc);
        acc = fmaxf(acc, 0.0f);
        osh[tid][d] = acc;
        if (writeT) outT[(size_t)n * SLAB_ + (size_t)d * B_ + b] = acc;
    }
    __syncthreads();

    float4* region4 = (float4*)(out + (size_t)n * SLAB_ + (size_t)(bt * 256) * D_);
#pragma unroll
    for (int j = 0; j < 4; ++j) {
        int i   = j * 256 + tid;
        int row = i >> 2;
        int c0  = (i & 3) * 4;
        float4 w;
        w.x = osh[row][c0 + 0];
        w.y = osh[row][c0 + 1];
        w.z = osh[row][c0 + 2];
        w.w = osh[row][c0 + 3];
        region4[i] = w;
    }
}

extern "C" void kernel_launch(void* const* d_in, const int* in_sizes, int n_in,
                              void* d_out, int out_size, void* d_ws, size_t ws_size,
                              hipStream_t stream) {
    const float* x     = (const float*)d_in[0];
    const float* trace = (const float*)d_in[1];
    const int*   sn    = (const int*)d_in[2];
    const int*   sf    = (const int*)d_in[3];
    const float* W     = (const float*)d_in[4];
    const float* bias  = (const float*)d_in[5];
    float*       out   = (float*)d_out;

    static int use_fused = -1;
    if (use_fused < 0) {
        hipError_t e = hipFuncSetAttribute(
            reinterpret_cast<const void*>(fused3_kernel),
            hipFuncAttributeMaxDynamicSharedMemorySize, 131072);
        if (e != hipSuccess) {
            (void)hipGetLastError();   // clear sticky error
            use_fused = 0;
        } else {
            use_fused = 1;
        }
    }

    const size_t wt_elems  = (size_t)N_ * D_ * K_;                  // 524288
    const size_t fused_ws  = sizeof(float) * wt_elems
                           + sizeof(uint32_t) * (size_t)N_ * K_;    // 2 MB + 128 KB

    if (use_fused == 1 && ws_size >= fused_ws) {
        float*    Wt   = (float*)d_ws;
        uint32_t* meta = (uint32_t*)(Wt + wt_elems);
        prep_kernel<<<N_, 512, 0, stream>>>(W, sn, sf, Wt, meta);
        fused3_kernel<<<B_ / 8, 1024, 131072, stream>>>(x, trace, meta, Wt, bias, out);
        return;
    }

    // ---------------- fallback: tiered implementation ----------------
    const size_t xT_elems  = (size_t)D_ * B_;
    const size_t big_elems = (size_t)N_ * SLAB_;
    const size_t needA = sizeof(float) * (xT_elems + 2 * big_elems);
    const size_t needB = sizeof(float) * (xT_elems + 1 * big_elems);

    float* ws = (float*)d_ws;

    if (ws_size >= needA) {
        float* xT     = ws;
        float* traceT = ws + xT_elems;
        float* outT   = traceT + big_elems;

        transpose_bd<<<N_ * 32 + 32, 256, 0, stream>>>(trace, x, traceT, xT);
        for (int l = 0; l < L_; ++l) {
            layer_kernel<<<M_ * 8, 256, 0, stream>>>(
                l,
                xT,     B_, 1,
                traceT, B_, 1,
                outT,   B_, 1,
                sn, sf, W, bias, out, outT, 1);
        }
    } else if (ws_size >= needB) {
        float* xT     = ws;
        float* traceT = ws + xT_elems;

        transpose_bd<<<N_ * 32 + 32, 256, 0, stream>>>(trace, x, traceT, xT);
        for (int l = 0; l < L_; ++l) {
            layer_kernel<<<M_ * 8, 256, 0, stream>>>(
                l,
                xT,     B_, 1,
                traceT, B_, 1,
                out,    1,  D_,
                sn, sf, W, bias, out, nullptr, 0);
        }
    } else {
        for (int l = 0; l < L_; ++l) {
            layer_kernel<<<M_ * 8, 256, 0, stream>>>(
                l,
                x,     1, D_,
                trace, 1, D_,
                out,   1, D_,
                sn, sf, W, bias, out, nullptr, 0);
        }
    }
}

// Round 4
// 505.228 us; speedup vs baseline: 1.3319x; 1.3319x over previous
//
#include <hip/hip_runtime.h>
#include <hip/hip_bf16.h>
#include <stdint.h>

#define L_ 8
#define M_ 128
#define K_ 32
#define D_ 16
#define B_ 2048
#define N_ 1024           // L_*M_
#define SLAB_ 32768       // B_*D_ elements per node slab

// Workspace float arena layout (offsets in floats):
#define WSF_XT    0u                          // xT[f][b]            : 32768
#define WSF_TRT   32768u                      // traceT[n][f][b]     : 33554432
#define WSF_OUTT  (32768u + 33554432u)        // outT[n<896][f][b]   : 29360128
#define WSF_WT    (WSF_OUTT + 29360128u)      // Wt[n][k][d]         : 524288
#define WSF_TOTAL (WSF_WT + 524288u)          // 63471616 floats
// meta (uint32, N_*K_ entries) lives right after the float arena.
#define WS_NEED_BYTES ((size_t)WSF_TOTAL * 4 + (size_t)N_ * K_ * 4)

// ===========================================================================
// FUSED PER-B PATH v4: transposed gathers from a single workspace arena.
// ---------------------------------------------------------------------------
// All gather sources (traceT, xT, outT-state) are [.][f][b] so a (n,k) gather
// for the block's 8 columns is 32 CONTIGUOUS bytes (fix for v3's 1.6 GB
// over-fetch: native layout used 4 B of each 64 B line). meta[n][k] holds a
// single float-offset into the arena -> gather = 1 uint load + 1 float4 load.
// State written transposed by the owning block itself (same-CU coherence via
// __syncthreads, proven in v3). Native out written as full 64 B lines.
// LDS G is k-major [k][m][8] (v3's FMA read pattern: 0 bank conflicts).
// ===========================================================================

__global__ __launch_bounds__(512) void prep_kernel(const float* __restrict__ W,
                                                   const int* __restrict__ sn,
                                                   const int* __restrict__ sf,
                                                   float* __restrict__ wsf) {
    int n = blockIdx.x;
    int t = threadIdx.x;          // 512 = D_*K_ ; t = d*32 + k
    int d = t >> 5;
    int k = t & 31;
    // W[n][d][k] -> Wt[n][k][d]
    wsf[WSF_WT + (size_t)n * 512 + k * 16 + d] = W[(size_t)n * 512 + t];
    if (t < K_) {
        int s = sn[(size_t)n * K_ + t];
        int f = sf[(size_t)n * K_ + t];
        int l = n >> 7;
        uint32_t off;
        if (s == 0) {
            off = WSF_XT + (uint32_t)(f * B_);
        } else if (s > (l << 7)) {
            off = WSF_TRT + (uint32_t)((s - 1) * SLAB_ + f * B_);
        } else {
            off = WSF_OUTT + (uint32_t)((s - 1) * SLAB_ + f * B_);
        }
        // k-major pair layout within the layer: p = k*128 + (n%128)
        uint32_t* meta = (uint32_t*)(wsf + WSF_TOTAL);
        meta[((uint32_t)(n >> 7) << 12) + ((uint32_t)t << 7) + (uint32_t)(n & 127)] = off;
    }
}

__global__ __launch_bounds__(1024) void fused4_kernel(
    float* __restrict__ wsf, const float* __restrict__ bias,
    float* __restrict__ out)
{
    extern __shared__ float G[];      // [K_=32][M_=128][8] floats = 131072 B

    int tid = threadIdx.x;
    int bb0 = blockIdx.x << 3;        // first of this block's 8 columns

    const uint32_t* meta = (const uint32_t*)(wsf + WSF_TOTAL);

    // FMA-phase coords
    int m2 = tid >> 3;                // node-in-layer
    int dq = (tid >> 1) & 3;          // d quarter (4 features)
    int bq = tid & 1;                 // b half (4 columns)

    for (int l = 0; l < L_; ++l) {
        if (l) __syncthreads();       // prev FMA done with G; outT writes drained

        // ---------------- gather phase -------------------------------------
        // load index i = jj*1024 + tid; pair p = i>>1 (k-major), half = tid&1.
        {
            const uint32_t* mpl = meta + (l << 12);
            float4 gv[8];
#pragma unroll
            for (int jj = 0; jj < 8; ++jj) {
                uint32_t off = mpl[(jj << 9) + (tid >> 1)];
                gv[jj] = *((const float4*)(wsf + off + bb0) + (tid & 1));
            }
            float4* G4 = (float4*)G;
#pragma unroll
            for (int jj = 0; jj < 8; ++jj) {
                G4[(jj << 10) + tid] = gv[jj];   // contiguous stride-16B writes
            }
        }
        __syncthreads();

        // ---------------- FMA phase ----------------------------------------
        {
            int n = (l << 7) + m2;
            float4 bv = *(const float4*)(bias + ((size_t)n << 4) + (dq << 2));
            // acc[d 0..3][b 0..3]
            float a00 = bv.x, a01 = bv.x, a02 = bv.x, a03 = bv.x;
            float a10 = bv.y, a11 = bv.y, a12 = bv.y, a13 = bv.y;
            float a20 = bv.z, a21 = bv.z, a22 = bv.z, a23 = bv.z;
            float a30 = bv.w, a31 = bv.w, a32 = bv.w, a33 = bv.w;

            const float4* wb = (const float4*)(wsf + WSF_WT + ((size_t)n << 9)) + dq;
            const float*  gk = G + (m2 << 3) + (bq << 2);
#pragma unroll
            for (int k = 0; k < K_; ++k) {
                float4 g4 = *(const float4*)(gk + (k << 10));   // 4 b columns
                float4 w  = wb[k << 2];                          // 4 d features
                a00 = fmaf(g4.x, w.x, a00); a01 = fmaf(g4.y, w.x, a01);
                a02 = fmaf(g4.z, w.x, a02); a03 = fmaf(g4.w, w.x, a03);
                a10 = fmaf(g4.x, w.y, a10); a11 = fmaf(g4.y, w.y, a11);
                a12 = fmaf(g4.z, w.y, a12); a13 = fmaf(g4.w, w.y, a13);
                a20 = fmaf(g4.x, w.z, a20); a21 = fmaf(g4.y, w.z, a21);
                a22 = fmaf(g4.z, w.z, a22); a23 = fmaf(g4.w, w.z, a23);
                a30 = fmaf(g4.x, w.w, a30); a31 = fmaf(g4.y, w.w, a31);
                a32 = fmaf(g4.z, w.w, a32); a33 = fmaf(g4.w, w.w, a33);
            }
            a00 = fmaxf(a00, 0.f); a01 = fmaxf(a01, 0.f); a02 = fmaxf(a02, 0.f); a03 = fmaxf(a03, 0.f);
            a10 = fmaxf(a10, 0.f); a11 = fmaxf(a11, 0.f); a12 = fmaxf(a12, 0.f); a13 = fmaxf(a13, 0.f);
            a20 = fmaxf(a20, 0.f); a21 = fmaxf(a21, 0.f); a22 = fmaxf(a22, 0.f); a23 = fmaxf(a23, 0.f);
            a30 = fmaxf(a30, 0.f); a31 = fmaxf(a31, 0.f); a32 = fmaxf(a32, 0.f); a33 = fmaxf(a33, 0.f);

            // -------- native out: full 64 B lines (f-major per column) ------
            {
                float* op = out + ((((size_t)n << 11) + bb0 + (bq << 2)) << 4) + (dq << 2);
                *(float4*)(op)      = make_float4(a00, a10, a20, a30);  // col bq*4+0
                *(float4*)(op + 16) = make_float4(a01, a11, a21, a31);  // col bq*4+1
                *(float4*)(op + 32) = make_float4(a02, a12, a22, a32);  // col bq*4+2
                *(float4*)(op + 48) = make_float4(a03, a13, a23, a33);  // col bq*4+3
            }

            // -------- transposed state (b-major per feature), layers 0..6 ---
            if (l < L_ - 1) {
                float* tp = wsf + WSF_OUTT + ((size_t)n << 15) + ((size_t)(dq << 2)) * B_
                          + bb0 + (bq << 2);
                *(float4*)(tp)          = make_float4(a00, a01, a02, a03);  // f = dq*4+0
                *(float4*)(tp + B_)     = make_float4(a10, a11, a12, a13);  // f = dq*4+1
                *(float4*)(tp + 2 * B_) = make_float4(a20, a21, a22, a23);  // f = dq*4+2
                *(float4*)(tp + 3 * B_) = make_float4(a30, a31, a32, a33);  // f = dq*4+3
            }
        }
    }
}

// ===========================================================================
// Transpose (B_, D_) slabs into (D_, B_) layout (also used by fallback).
// ===========================================================================

__global__ __launch_bounds__(256) void transpose_bd(const float* __restrict__ trace,
                                                    const float* __restrict__ x,
                                                    float* __restrict__ traceT,
                                                    float* __restrict__ xT) {
    int blk = blockIdx.x;
    const float* src;
    float* dst;
    int bt;
    if (blk < N_ * 32) {
        int n = blk >> 5;
        src = trace + (size_t)n * SLAB_;
        dst = traceT + (size_t)n * SLAB_;
        bt  = blk & 31;
    } else {
        src = x;
        dst = xT;
        bt  = blk - N_ * 32;
    }
    int b0 = bt * 64;

    __shared__ float lds[D_][65];

    int tid = threadIdx.x;
    const float4* s4 = (const float4*)src;
    int b  = tid >> 2;
    int dq = tid & 3;
    float4 v = s4[(size_t)(b0 + b) * 4 + dq];
    lds[dq * 4 + 0][b] = v.x;
    lds[dq * 4 + 1][b] = v.y;
    lds[dq * 4 + 2][b] = v.z;
    lds[dq * 4 + 3][b] = v.w;
    __syncthreads();

    int d  = tid >> 4;
    int bq = tid & 15;
    float4 w;
    w.x = lds[d][bq * 4 + 0];
    w.y = lds[d][bq * 4 + 1];
    w.z = lds[d][bq * 4 + 2];
    w.w = lds[d][bq * 4 + 3];
    ((float4*)(dst + (size_t)d * B_ + b0))[bq] = w;
}

// ===========================================================================
// FALLBACK PATH (verified tiered implementation)
// ===========================================================================

__global__ __launch_bounds__(256) void layer_kernel(
    int l,
    const float* __restrict__ xbuf, int xfs, int xbs,
    const float* __restrict__ tbuf, int tfs, int tbs,
    const float* __restrict__ obuf, int ofs, int obs,
    const int* __restrict__ sn, const int* __restrict__ sf,
    const float* __restrict__ W, const float* __restrict__ bias,
    float* __restrict__ out, float* __restrict__ outT, int writeT)
{
    int m  = blockIdx.x >> 3;
    int bt = blockIdx.x & 7;
    int n  = l * M_ + m;
    int b  = bt * 256 + threadIdx.x;

    __shared__ float        Wsh[D_][K_];
    __shared__ float        bsh[D_];
    __shared__ const float* colp[K_];
    __shared__ int          colbs[K_];
    __shared__ float        osh[256][17];

    int tid = threadIdx.x;

    if (tid < 128) {
        ((float4*)&Wsh[0][0])[tid] = ((const float4*)(W + (size_t)n * D_ * K_))[tid];
    }
    if (tid < D_) bsh[tid] = bias[(size_t)n * D_ + tid];
    if (tid < K_) {
        int s = sn[(size_t)n * K_ + tid];
        int f = sf[(size_t)n * K_ + tid];
        const float* p;
        int bs;
        if (s == 0) {
            p  = xbuf + (size_t)f * xfs;
            bs = xbs;
        } else {
            int ls = (s - 1) >> 7;
            if (ls >= l) {
                p  = tbuf + (size_t)(s - 1) * SLAB_ + (size_t)f * tfs;
                bs = tbs;
            } else {
                p  = obuf + (size_t)(s - 1) * SLAB_ + (size_t)f * ofs;
                bs = obs;
            }
        }
        colp[tid]  = p;
        colbs[tid] = bs;
    }
    __syncthreads();

    float g[K_];
#pragma unroll
    for (int k = 0; k < K_; ++k) {
        g[k] = colp[k][(size_t)b * colbs[k]];
    }

#pragma unroll
    for (int d = 0; d < D_; ++d) {
        float acc = bsh[d];
#pragma unroll
        for (int k = 0; k < K_; ++k) acc = fmaf(g[k], Wsh[d][k], acc);
        acc = fmaxf(acc, 0.0f);
        osh[tid][d] = acc;
        if (writeT) outT[(size_t)n * SLAB_ + (size_t)d * B_ + b] = acc;
    }
    __syncthreads();

    float4* region4 = (float4*)(out + (size_t)n * SLAB_ + (size_t)(bt * 256) * D_);
#pragma unroll
    for (int j = 0; j < 4; ++j) {
        int i   = j * 256 + tid;
        int row = i >> 2;
        int c0  = (i & 3) * 4;
        float4 w;
        w.x = osh[row][c0 + 0];
        w.y = osh[row][c0 + 1];
        w.z = osh[row][c0 + 2];
        w.w = osh[row][c0 + 3];
        region4[i] = w;
    }
}

extern "C" void kernel_launch(void* const* d_in, const int* in_sizes, int n_in,
                              void* d_out, int out_size, void* d_ws, size_t ws_size,
                              hipStream_t stream) {
    const float* x     = (const float*)d_in[0];
    const float* trace = (const float*)d_in[1];
    const int*   sn    = (const int*)d_in[2];
    const int*   sf    = (const int*)d_in[3];
    const float* W     = (const float*)d_in[4];
    const float* bias  = (const float*)d_in[5];
    float*       out   = (float*)d_out;

    static int use_fused = -1;
    if (use_fused < 0) {
        hipError_t e = hipFuncSetAttribute(
            reinterpret_cast<const void*>(fused4_kernel),
            hipFuncAttributeMaxDynamicSharedMemorySize, 131072);
        if (e != hipSuccess) {
            (void)hipGetLastError();   // clear sticky error
            use_fused = 0;
        } else {
            use_fused = 1;
        }
    }

    if (use_fused == 1 && ws_size >= WS_NEED_BYTES) {
        float* wsf = (float*)d_ws;
        transpose_bd<<<N_ * 32 + 32, 256, 0, stream>>>(trace, x,
                                                       wsf + WSF_TRT, wsf + WSF_XT);
        prep_kernel<<<N_, 512, 0, stream>>>(W, sn, sf, wsf);
        fused4_kernel<<<B_ / 8, 1024, 131072, stream>>>(wsf, bias, out);
        return;
    }

    // ---------------- fallback: tiered implementation ----------------
    const size_t xT_elems  = (size_t)D_ * B_;
    const size_t big_elems = (size_t)N_ * SLAB_;
    const size_t needA = sizeof(float) * (xT_elems + 2 * big_elems);
    const size_t needB = sizeof(float) * (xT_elems + 1 * big_elems);

    float* ws = (float*)d_ws;

    if (ws_size >= needA) {
        float* xT     = ws;
        float* traceT = ws + xT_elems;
        float* outT   = traceT + big_elems;

        transpose_bd<<<N_ * 32 + 32, 256, 0, stream>>>(trace, x, traceT, xT);
        for (int l = 0; l < L_; ++l) {
            layer_kernel<<<M_ * 8, 256, 0, stream>>>(
                l,
                xT,     B_, 1,
                traceT, B_, 1,
                outT,   B_, 1,
                sn, sf, W, bias, out, outT, 1);
        }
    } else if (ws_size >= needB) {
        float* xT     = ws;
        float* traceT = ws + xT_elems;

        transpose_bd<<<N_ * 32 + 32, 256, 0, stream>>>(trace, x, traceT, xT);
        for (int l = 0; l < L_; ++l) {
            layer_kernel<<<M_ * 8, 256, 0, stream>>>(
                l,
                xT,     B_, 1,
                traceT, B_, 1,
                out,    1,  D_,
                sn, sf, W, bias, out, nullptr, 0);
        }
    } else {
        for (int l = 0; l < L_; ++l) {
            layer_kernel<<<M_ * 8, 256, 0, stream>>>(
                l,
                x,     1, D_,
                trace, 1, D_,
                out,   1, D_,
                sn, sf, W, bias, out, nullptr, 0);
        }
    }
}

// Round 6
// 407.157 us; speedup vs baseline: 1.6527x; 1.2409x over previous
//
#include <hip/hip_runtime.h>
#include <hip/hip_bf16.h>
#include <stdint.h>

#define L_ 8
#define M_ 128
#define K_ 32
#define D_ 16
#define B_ 2048
#define N_ 1024           // L_*M_
#define SLAB_ 32768       // B_*D_ elements per node slab

// Workspace float arena layout (offsets in floats):
#define WSF_XT    0u                          // xT[f][b]            : 32768
#define WSF_TRT   32768u                      // traceT[n][f][b]     : 33554432
#define WSF_OUTT  (32768u + 33554432u)        // outT[n<896][f][b]   : 29360128
#define WSF_WT    (WSF_OUTT + 29360128u)      // Wt[n][k][d]         : 524288
#define WSF_TOTAL (WSF_WT + 524288u)          // 63471616 floats
// meta (uint32, N_*K_ entries) lives right after the float arena.
#define WS_NEED_BYTES ((size_t)WSF_TOTAL * 4 + (size_t)N_ * K_ * 4)

// ===========================================================================
// v6: per-layer dispatches (temporal alignment + implicit cross-dispatch
// coherence), BBLK=16 columns per block -> every gather/store is a FULL
// 64 B line (fix for v4's 504 MB half-line over-fetch).
// ---------------------------------------------------------------------------
// Grid per layer = 256 blocks: (mh: layer half 0/1) x (bt: 128 b-tiles of 16
// cols). 1024 threads. LDS G[32 k][64 m][16 b] = 128 KiB.
//   gather: pair p = k*64+m6; 4 lanes (tid&3) read the pair's full 64 B line
//           from arena[off + bt*16 .. +16); meta holds plain float offsets.
//   FMA:    thread (m6=tid>>4, dq=(tid>>2)&3, bq=tid&3) -> 4 d x 4 b acc.
//   out:    4 dq-lanes per (node,col) -> full 64 B native line.
//   outT:   4 bq-lanes per (node,f-row) -> full 64 B transposed line (l<7).
// Per layer chip-wide: ~33.5 MB gather reads (each row once), ~31.5 MB writes.
// ===========================================================================

__global__ __launch_bounds__(512) void prep6_kernel(const float* __restrict__ W,
                                                    const int* __restrict__ sn,
                                                    const int* __restrict__ sf,
                                                    float* __restrict__ wsf) {
    int n = blockIdx.x;
    int t = threadIdx.x;          // 512 = D_*K_ ; t = d*32 + k
    int d = t >> 5;
    int k = t & 31;
    // W[n][d][k] -> Wt[n][k][d]
    wsf[WSF_WT + (size_t)n * 512 + k * 16 + d] = W[(size_t)n * 512 + t];
    if (t < K_) {
        int s = sn[(size_t)n * K_ + t];
        int f = sf[(size_t)n * K_ + t];
        int l = n >> 7;
        uint32_t off;
        if (s == 0) {
            off = WSF_XT + (uint32_t)(f * B_);
        } else if (s > (l << 7)) {
            off = WSF_TRT + (uint32_t)((s - 1) * SLAB_ + f * B_);
        } else {
            off = WSF_OUTT + (uint32_t)((s - 1) * SLAB_ + f * B_);
        }
        int mloc = n & 127;
        int mh   = mloc >> 6;
        int m6   = mloc & 63;
        uint32_t* meta = (uint32_t*)(wsf + WSF_TOTAL);
        // slice (l,mh): 2048 pairs, pair = k*64 + m6
        meta[((uint32_t)((l << 1) + mh) << 11) + (uint32_t)((t << 6) + m6)] = off;
    }
}

__global__ __launch_bounds__(1024) void layer6_kernel(
    int l, float* __restrict__ wsf, const float* __restrict__ bias,
    float* __restrict__ out)
{
    extern __shared__ float G[];      // [32][64][16] floats = 131072 B

    int tid = threadIdx.x;
    int mh  = blockIdx.x & 1;         // layer half (nodes mh*64 .. +64)
    int bt  = blockIdx.x >> 1;        // b-tile (16 cols)
    int b0  = bt << 4;

    const uint32_t* mpl = (const uint32_t*)(wsf + WSF_TOTAL)
                        + (((uint32_t)(l << 1) + mh) << 11);

    // ---------------- gather phase: full 64 B lines --------------------------
    {
        float4 gv[8];
#pragma unroll
        for (int jj = 0; jj < 8; ++jj) {
            uint32_t off = mpl[(jj << 8) + (tid >> 2)];
            gv[jj] = *((const float4*)(wsf + off + b0) + (tid & 3));
        }
        float4* G4 = (float4*)G;
#pragma unroll
        for (int jj = 0; jj < 8; ++jj) {
            G4[(jj << 10) + tid] = gv[jj];   // contiguous 1 KB per wave
        }
    }
    __syncthreads();

    // ---------------- FMA phase ---------------------------------------------
    int m6 = tid >> 4;                // node within half
    int dq = (tid >> 2) & 3;          // d quarter
    int bq = tid & 3;                 // col quad
    int n  = (l << 7) + (mh << 6) + m6;

    float4 bv = *(const float4*)(bias + ((size_t)n << 4) + (dq << 2));
    float a00 = bv.x, a01 = bv.x, a02 = bv.x, a03 = bv.x;
    float a10 = bv.y, a11 = bv.y, a12 = bv.y, a13 = bv.y;
    float a20 = bv.z, a21 = bv.z, a22 = bv.z, a23 = bv.z;
    float a30 = bv.w, a31 = bv.w, a32 = bv.w, a33 = bv.w;

    const float4* wb = (const float4*)(wsf + WSF_WT + ((size_t)n << 9)) + dq;
    const float*  gk = G + (m6 << 4) + (bq << 2);
#pragma unroll
    for (int k = 0; k < K_; ++k) {
        float4 g4 = *(const float4*)(gk + (k << 10));   // 4 cols
        float4 w  = wb[k << 2];                          // 4 d features
        a00 = fmaf(g4.x, w.x, a00); a01 = fmaf(g4.y, w.x, a01);
        a02 = fmaf(g4.z, w.x, a02); a03 = fmaf(g4.w, w.x, a03);
        a10 = fmaf(g4.x, w.y, a10); a11 = fmaf(g4.y, w.y, a11);
        a12 = fmaf(g4.z, w.y, a12); a13 = fmaf(g4.w, w.y, a13);
        a20 = fmaf(g4.x, w.z, a20); a21 = fmaf(g4.y, w.z, a21);
        a22 = fmaf(g4.z, w.z, a22); a23 = fmaf(g4.w, w.z, a23);
        a30 = fmaf(g4.x, w.w, a30); a31 = fmaf(g4.y, w.w, a31);
        a32 = fmaf(g4.z, w.w, a32); a33 = fmaf(g4.w, w.w, a33);
    }
    a00 = fmaxf(a00, 0.f); a01 = fmaxf(a01, 0.f); a02 = fmaxf(a02, 0.f); a03 = fmaxf(a03, 0.f);
    a10 = fmaxf(a10, 0.f); a11 = fmaxf(a11, 0.f); a12 = fmaxf(a12, 0.f); a13 = fmaxf(a13, 0.f);
    a20 = fmaxf(a20, 0.f); a21 = fmaxf(a21, 0.f); a22 = fmaxf(a22, 0.f); a23 = fmaxf(a23, 0.f);
    a30 = fmaxf(a30, 0.f); a31 = fmaxf(a31, 0.f); a32 = fmaxf(a32, 0.f); a33 = fmaxf(a33, 0.f);

    // -------- native out: 4 dq-lanes x 16 B = full 64 B line per (n,col) ----
    {
        float* op = out + ((((size_t)n << 11) + b0 + (bq << 2)) << 4) + (dq << 2);
        *(float4*)(op)      = make_float4(a00, a10, a20, a30);  // col +0
        *(float4*)(op + 16) = make_float4(a01, a11, a21, a31);  // col +1
        *(float4*)(op + 32) = make_float4(a02, a12, a22, a32);  // col +2
        *(float4*)(op + 48) = make_float4(a03, a13, a23, a33);  // col +3
    }

    // -------- transposed state: 4 bq-lanes x 16 B = full line per (n,f) ----
    if (l < L_ - 1) {
        float* tp = wsf + WSF_OUTT + ((size_t)n << 15) + ((size_t)(dq << 2)) * B_
                  + b0 + (bq << 2);
        *(float4*)(tp)          = make_float4(a00, a01, a02, a03);  // f = dq*4+0
        *(float4*)(tp + B_)     = make_float4(a10, a11, a12, a13);  // f = dq*4+1
        *(float4*)(tp + 2 * B_) = make_float4(a20, a21, a22, a23);  // f = dq*4+2
        *(float4*)(tp + 3 * B_) = make_float4(a30, a31, a32, a33);  // f = dq*4+3
    }
}

// ===========================================================================
// Transpose (B_, D_) slabs into (D_, B_) layout (also used by fallback).
// ===========================================================================

__global__ __launch_bounds__(256) void transpose_bd(const float* __restrict__ trace,
                                                    const float* __restrict__ x,
                                                    float* __restrict__ traceT,
                                                    float* __restrict__ xT) {
    int blk = blockIdx.x;
    const float* src;
    float* dst;
    int bt;
    if (blk < N_ * 32) {
        int n = blk >> 5;
        src = trace + (size_t)n * SLAB_;
        dst = traceT + (size_t)n * SLAB_;
        bt  = blk & 31;
    } else {
        src = x;
        dst = xT;
        bt  = blk - N_ * 32;
    }
    int b0 = bt * 64;

    __shared__ float lds[D_][65];

    int tid = threadIdx.x;
    const float4* s4 = (const float4*)src;
    int b  = tid >> 2;
    int dq = tid & 3;
    float4 v = s4[(size_t)(b0 + b) * 4 + dq];
    lds[dq * 4 + 0][b] = v.x;
    lds[dq * 4 + 1][b] = v.y;
    lds[dq * 4 + 2][b] = v.z;
    lds[dq * 4 + 3][b] = v.w;
    __syncthreads();

    int d  = tid >> 4;
    int bq = tid & 15;
    float4 w;
    w.x = lds[d][bq * 4 + 0];
    w.y = lds[d][bq * 4 + 1];
    w.z = lds[d][bq * 4 + 2];
    w.w = lds[d][bq * 4 + 3];
    ((float4*)(dst + (size_t)d * B_ + b0))[bq] = w;
}

// ===========================================================================
// FALLBACK PATH (verified tiered implementation)
// ===========================================================================

__global__ __launch_bounds__(256) void layer_kernel(
    int l,
    const float* __restrict__ xbuf, int xfs, int xbs,
    const float* __restrict__ tbuf, int tfs, int tbs,
    const float* __restrict__ obuf, int ofs, int obs,
    const int* __restrict__ sn, const int* __restrict__ sf,
    const float* __restrict__ W, const float* __restrict__ bias,
    float* __restrict__ out, float* __restrict__ outT, int writeT)
{
    int m  = blockIdx.x >> 3;
    int bt = blockIdx.x & 7;
    int n  = l * M_ + m;
    int b  = bt * 256 + threadIdx.x;

    __shared__ float        Wsh[D_][K_];
    __shared__ float        bsh[D_];
    __shared__ const float* colp[K_];
    __shared__ int          colbs[K_];
    __shared__ float        osh[256][17];

    int tid = threadIdx.x;

    if (tid < 128) {
        ((float4*)&Wsh[0][0])[tid] = ((const float4*)(W + (size_t)n * D_ * K_))[tid];
    }
    if (tid < D_) bsh[tid] = bias[(size_t)n * D_ + tid];
    if (tid < K_) {
        int s = sn[(size_t)n * K_ + tid];
        int f = sf[(size_t)n * K_ + tid];
        const float* p;
        int bs;
        if (s == 0) {
            p  = xbuf + (size_t)f * xfs;
            bs = xbs;
        } else {
            int ls = (s - 1) >> 7;
            if (ls >= l) {
                p  = tbuf + (size_t)(s - 1) * SLAB_ + (size_t)f * tfs;
                bs = tbs;
            } else {
                p  = obuf + (size_t)(s - 1) * SLAB_ + (size_t)f * ofs;
                bs = obs;
            }
        }
        colp[tid]  = p;
        colbs[tid] = bs;
    }
    __syncthreads();

    float g[K_];
#pragma unroll
    for (int k = 0; k < K_; ++k) {
        g[k] = colp[k][(size_t)b * colbs[k]];
    }

#pragma unroll
    for (int d = 0; d < D_; ++d) {
        float acc = bsh[d];
#pragma unroll
        for (int k = 0; k < K_; ++k) acc = fmaf(g[k], Wsh[d][k], acc);
        acc = fmaxf(acc, 0.0f);
        osh[tid][d] = acc;
        if (writeT) outT[(size_t)n * SLAB_ + (size_t)d * B_ + b] = acc;
    }
    __syncthreads();

    float4* region4 = (float4*)(out + (size_t)n * SLAB_ + (size_t)(bt * 256) * D_);
#pragma unroll
    for (int j = 0; j < 4; ++j) {
        int i   = j * 256 + tid;
        int row = i >> 2;
        int c0  = (i & 3) * 4;
        float4 w;
        w.x = osh[row][c0 + 0];
        w.y = osh[row][c0 + 1];
        w.z = osh[row][c0 + 2];
        w.w = osh[row][c0 + 3];
        region4[i] = w;
    }
}

extern "C" void kernel_launch(void* const* d_in, const int* in_sizes, int n_in,
                              void* d_out, int out_size, void* d_ws, size_t ws_size,
                              hipStream_t stream) {
    const float* x     = (const float*)d_in[0];
    const float* trace = (const float*)d_in[1];
    const int*   sn    = (const int*)d_in[2];
    const int*   sf    = (const int*)d_in[3];
    const float* W     = (const float*)d_in[4];
    const float* bias  = (const float*)d_in[5];
    float*       out   = (float*)d_out;

    static int use_fused = -1;
    if (use_fused < 0) {
        hipError_t e = hipFuncSetAttribute(
            reinterpret_cast<const void*>(layer6_kernel),
            hipFuncAttributeMaxDynamicSharedMemorySize, 131072);
        if (e != hipSuccess) {
            (void)hipGetLastError();   // clear sticky error
            use_fused = 0;
        } else {
            use_fused = 1;
        }
    }

    if (use_fused == 1 && ws_size >= WS_NEED_BYTES) {
        float* wsf = (float*)d_ws;
        transpose_bd<<<N_ * 32 + 32, 256, 0, stream>>>(trace, x,
                                                       wsf + WSF_TRT, wsf + WSF_XT);
        prep6_kernel<<<N_, 512, 0, stream>>>(W, sn, sf, wsf);
        for (int l = 0; l < L_; ++l) {
            layer6_kernel<<<256, 1024, 131072, stream>>>(l, wsf, bias, out);
        }
        return;
    }

    // ---------------- fallback: tiered implementation ----------------
    const size_t xT_elems  = (size_t)D_ * B_;
    const size_t big_elems = (size_t)N_ * SLAB_;
    const size_t needA = sizeof(float) * (xT_elems + 2 * big_elems);
    const size_t needB = sizeof(float) * (xT_elems + 1 * big_elems);

    float* ws = (float*)d_ws;

    if (ws_size >= needA) {
        float* xT     = ws;
        float* traceT = ws + xT_elems;
        float* outT   = traceT + big_elems;

        transpose_bd<<<N_ * 32 + 32, 256, 0, stream>>>(trace, x, traceT, xT);
        for (int l = 0; l < L_; ++l) {
            layer_kernel<<<M_ * 8, 256, 0, stream>>>(
                l,
                xT,     B_, 1,
                traceT, B_, 1,
                outT,   B_, 1,
                sn, sf, W, bias, out, outT, 1);
        }
    } else if (ws_size >= needB) {
        float* xT     = ws;
        float* traceT = ws + xT_elems;

        transpose_bd<<<N_ * 32 + 32, 256, 0, stream>>>(trace, x, traceT, xT);
        for (int l = 0; l < L_; ++l) {
            layer_kernel<<<M_ * 8, 256, 0, stream>>>(
                l,
                xT,     B_, 1,
                traceT, B_, 1,
                out,    1,  D_,
                sn, sf, W, bias, out, nullptr, 0);
        }
    } else {
        for (int l = 0; l < L_; ++l) {
            layer_kernel<<<M_ * 8, 256, 0, stream>>>(
                l,
                x,     1, D_,
                trace, 1, D_,
                out,   1, D_,
                sn, sf, W, bias, out, nullptr, 0);
        }
    }
}